// Round 1
// baseline (81.713 us; speedup 1.0000x reference)
//
#include <hip/hip_runtime.h>
#include <stdint.h>

// Problem: MulticlassDice — N=8 samples, C=8 classes, 512x512 pixels.
// Entire computation = 192 histogram counters (count_in, count_tg, inter per (n,c)),
// then a tiny epilogue. Memory-bound: 16 MiB read -> ~2.7 us roofline.

#define NCLS   8
#define NSAMP  8
#define PIX    (512 * 512)
#define SMOOTHF 1e-5f

typedef unsigned long long u64;
typedef unsigned int u32;

// ws layout: u32 cnt[NSAMP][3][NCLS]  (set 0 = count_in, 1 = count_tg, 2 = inter)
// 8 * 24 = 192 u32 = 768 bytes.

// 64 blocks per sample, 256 threads, 4 x int4 per thread = 16 pixels/thread.
// Per-thread per-class count <= 16 -> fits 8-bit SWAR field.
// 64-lane wave sum <= 1024 -> fits 16-bit SWAR field.
__global__ __launch_bounds__(256) void dice_count(const int* __restrict__ in,
                                                  const int* __restrict__ tg,
                                                  u32* __restrict__ cnt) {
    const int n = blockIdx.y;
    const int t = threadIdx.x;
    const int4* in4 = (const int4*)(in + (size_t)n * PIX);
    const int4* tg4 = (const int4*)(tg + (size_t)n * PIX);
    const int base = blockIdx.x * 1024;  // int4 units; 64 blocks * 1024 = 65536 int4 = 262144 px

    u64 pin = 0, ptg = 0, pix = 0;  // 8-bit field per class
#pragma unroll
    for (int i = 0; i < 4; ++i) {
        int4 a = in4[base + i * 256 + t];
        int4 b = tg4[base + i * 256 + t];
        u64 ax = 1ull << (a.x * 8), ay = 1ull << (a.y * 8);
        u64 az = 1ull << (a.z * 8), aw = 1ull << (a.w * 8);
        pin += ax + ay + az + aw;
        ptg += (1ull << (b.x * 8)) + (1ull << (b.y * 8)) +
               (1ull << (b.z * 8)) + (1ull << (b.w * 8));
        if (a.x == b.x) pix += ax;
        if (a.y == b.y) pix += ay;
        if (a.z == b.z) pix += az;
        if (a.w == b.w) pix += aw;
    }

    // Split 8-bit fields into 16-bit fields (even classes / odd classes) so a
    // full 64-lane butterfly cannot overflow.
    const u64 M = 0x00FF00FF00FF00FFull;
    u64 v[6];
    v[0] = pin & M;        // classes 0,2,4,6 of count_in
    v[1] = (pin >> 8) & M; // classes 1,3,5,7
    v[2] = ptg & M;
    v[3] = (ptg >> 8) & M;
    v[4] = pix & M;
    v[5] = (pix >> 8) & M;

#pragma unroll
    for (int off = 1; off < 64; off <<= 1) {
#pragma unroll
        for (int j = 0; j < 6; ++j)
            v[j] += (u64)__shfl_xor((unsigned long long)v[j], off, 64);
    }

    // After butterfly every lane of the wave holds the full wave sum.
    // Lanes 0..23: set = lane/8, class = lane%8 -> one atomic each.
    const int lane = t & 63;
    if (lane < 24) {
        const int set = lane >> 3;
        const int c   = lane & 7;
        u64 pk = v[set * 2 + (c & 1)];
        u32 val = (u32)((pk >> (16 * (c >> 1))) & 0xFFFFull);
        atomicAdd(&cnt[n * 24 + set * 8 + c], val);
    }
}

// One wave. lane -> (n = lane/8, c = lane%8).
__global__ __launch_bounds__(64) void dice_final(const u32* __restrict__ cnt,
                                                 const float* __restrict__ w,
                                                 float* __restrict__ out) {
    const int lane = threadIdx.x;
    const int n = lane >> 3;
    const int c = lane & 7;
    float cin = (float)cnt[n * 24 + 0 + c];
    float ctg = (float)cnt[n * 24 + 8 + c];
    float itr = (float)cnt[n * 24 + 16 + c];
    float dice = (2.0f * itr + SMOOTHF) / (cin + ctg + SMOOTHF);

    // Sum over n (lanes differing in bits 3..5 share c).
    dice += __shfl_xor(dice, 8, 64);
    dice += __shfl_xor(dice, 16, 64);
    dice += __shfl_xor(dice, 32, 64);
    float mean_c = dice * 0.125f;  // every lane: mean dice for its class c

    if (lane < 8) out[1 + lane] = mean_c;  // lanes 0..7 have c == lane

    float ws = w[c] * mean_c;
    ws += __shfl_xor(ws, 1, 64);
    ws += __shfl_xor(ws, 2, 64);
    ws += __shfl_xor(ws, 4, 64);
    if (lane == 0) out[0] = ws;
}

extern "C" void kernel_launch(void* const* d_in, const int* in_sizes, int n_in,
                              void* d_out, int out_size, void* d_ws, size_t ws_size,
                              hipStream_t stream) {
    const int*   in  = (const int*)d_in[0];
    const int*   tg  = (const int*)d_in[1];
    const float* w   = (const float*)d_in[2];
    float*       out = (float*)d_out;
    u32*         cnt = (u32*)d_ws;

    // ws is re-poisoned to 0xAA before every launch -> must zero the counters.
    hipMemsetAsync(d_ws, 0, NSAMP * 24 * sizeof(u32), stream);

    dice_count<<<dim3(64, NSAMP), 256, 0, stream>>>(in, tg, cnt);
    dice_final<<<1, 64, 0, stream>>>(cnt, w, out);
}

// Round 2
// 74.011 us; speedup vs baseline: 1.1041x; 1.1041x over previous
//
#include <hip/hip_runtime.h>
#include <stdint.h>

// MulticlassDice — N=8 samples, C=8 classes, 512x512 px, int32 labels 0..7.
// Whole computation = 192 histogram counters (count_in, count_tg, inter per
// (n,c)) + tiny epilogue. 16 MiB stream -> ~2.7 us HBM floor.
//
// R2: no hipMemsetAsync node. Each block writes its own partial slot
// (unconditional full overwrite of poisoned ws), dice_final reduces partials.
// 2 graph nodes, zero global atomics.

#define NCLS    8
#define NSAMP   8
#define PIX     (512 * 512)
#define BLKS    64            // blocks per sample
#define SMOOTHF 1e-5f

typedef unsigned long long u64;
typedef unsigned int u32;

// ws layout: u32 partial[NSAMP*BLKS][24]
//   counter index i = set*8 + c,  set 0 = count_in, 1 = count_tg, 2 = inter.

// grid (BLKS, NSAMP) x 256 threads; 16 px/thread via 4 x int4 per array.
// Per-thread per-class count <= 16 (8-bit SWAR field safe).
// Butterfly rounds 1-3 on 8-bit fields (max 16*8=128 <= 255), then split to
// 16-bit fields for rounds 4-6 (max 16*64=1024 <= 65535).
__global__ __launch_bounds__(256) void dice_count(const int* __restrict__ in,
                                                  const int* __restrict__ tg,
                                                  u32* __restrict__ partial) {
    const int n = blockIdx.y;
    const int t = threadIdx.x;
    const int4* in4 = (const int4*)(in + (size_t)n * PIX);
    const int4* tg4 = (const int4*)(tg + (size_t)n * PIX);
    const int base = blockIdx.x * 1024;  // int4 units; 64 blk * 1024 * 4 = 262144 px

    u64 pin = 0, ptg = 0, pix = 0;  // 8-bit field per class
#pragma unroll
    for (int i = 0; i < 4; ++i) {
        int4 a = in4[base + i * 256 + t];
        int4 b = tg4[base + i * 256 + t];
        u64 ax = 1ull << (a.x * 8), ay = 1ull << (a.y * 8);
        u64 az = 1ull << (a.z * 8), aw = 1ull << (a.w * 8);
        pin += ax + ay + az + aw;
        ptg += (1ull << (b.x * 8)) + (1ull << (b.y * 8)) +
               (1ull << (b.z * 8)) + (1ull << (b.w * 8));
        if (a.x == b.x) pix += ax;
        if (a.y == b.y) pix += ay;
        if (a.z == b.z) pix += az;
        if (a.w == b.w) pix += aw;
    }

    // Rounds 1-3 (offsets 1,2,4) on packed 8-bit fields: 3 u64 shuffles/round.
#pragma unroll
    for (int off = 1; off <= 4; off <<= 1) {
        pin += (u64)__shfl_xor((unsigned long long)pin, off, 64);
        ptg += (u64)__shfl_xor((unsigned long long)ptg, off, 64);
        pix += (u64)__shfl_xor((unsigned long long)pix, off, 64);
    }

    // Split 8-bit -> 16-bit fields (even classes low, odd classes high word set).
    const u64 M = 0x00FF00FF00FF00FFull;
    u64 v[6];
    v[0] = pin & M;        // count_in, classes 0,2,4,6
    v[1] = (pin >> 8) & M; // count_in, classes 1,3,5,7
    v[2] = ptg & M;
    v[3] = (ptg >> 8) & M;
    v[4] = pix & M;
    v[5] = (pix >> 8) & M;

    // Rounds 4-6 (offsets 8,16,32).
#pragma unroll
    for (int off = 8; off <= 32; off <<= 1) {
#pragma unroll
        for (int j = 0; j < 6; ++j)
            v[j] += (u64)__shfl_xor((unsigned long long)v[j], off, 64);
    }

    // Every lane now holds the full wave sum. Combine 4 waves via LDS.
    __shared__ u32 sm[4 * 24];
    const int wave = t >> 6;
    const int lane = t & 63;
    if (lane < 24) {
        const int set = lane >> 3;
        const int c   = lane & 7;
        u64 pk = v[set * 2 + (c & 1)];
        sm[wave * 24 + lane] = (u32)((pk >> (16 * (c >> 1))) & 0xFFFFull);
    }
    __syncthreads();
    if (t < 24) {
        u32 s = sm[t] + sm[24 + t] + sm[48 + t] + sm[72 + t];
        partial[((size_t)(n * BLKS + blockIdx.x)) * 24 + t] = s;
    }
}

// One block, 192 threads (3 waves). Thread t -> (n = t/24, i = t%24):
// sum 64 block-partials, then wave 0 does the dice epilogue.
__global__ __launch_bounds__(192) void dice_final(const u32* __restrict__ partial,
                                                  const float* __restrict__ w,
                                                  float* __restrict__ out) {
    const int t = threadIdx.x;
    __shared__ u32 cnt[NSAMP * 24];

    const int n = t / 24;
    const int i = t - n * 24;
    u32 s = 0;
#pragma unroll 8
    for (int b = 0; b < BLKS; ++b)
        s += partial[((size_t)(n * BLKS + b)) * 24 + i];
    cnt[n * 24 + i] = s;
    __syncthreads();

    if (t < 64) {
        const int sn = t >> 3;
        const int c  = t & 7;
        float cin = (float)cnt[sn * 24 + 0 + c];
        float ctg = (float)cnt[sn * 24 + 8 + c];
        float itr = (float)cnt[sn * 24 + 16 + c];
        float dice = (2.0f * itr + SMOOTHF) / (cin + ctg + SMOOTHF);

        // Sum over samples (lanes differing in bits 3..5 share c).
        dice += __shfl_xor(dice, 8, 64);
        dice += __shfl_xor(dice, 16, 64);
        dice += __shfl_xor(dice, 32, 64);
        float mean_c = dice * 0.125f;

        if (t < 8) out[1 + t] = mean_c;

        float ws = w[c] * mean_c;
        ws += __shfl_xor(ws, 1, 64);
        ws += __shfl_xor(ws, 2, 64);
        ws += __shfl_xor(ws, 4, 64);
        if (t == 0) out[0] = ws;
    }
}

extern "C" void kernel_launch(void* const* d_in, const int* in_sizes, int n_in,
                              void* d_out, int out_size, void* d_ws, size_t ws_size,
                              hipStream_t stream) {
    const int*   in  = (const int*)d_in[0];
    const int*   tg  = (const int*)d_in[1];
    const float* w   = (const float*)d_in[2];
    float*       out = (float*)d_out;
    u32*         partial = (u32*)d_ws;  // fully overwritten every call

    dice_count<<<dim3(BLKS, NSAMP), 256, 0, stream>>>(in, tg, partial);
    dice_final<<<1, 192, 0, stream>>>(partial, w, out);
}